// Round 7
// baseline (41.540 us; speedup 1.0000x reference)
//
#include <hip/hip_runtime.h>
#include <hip/hip_bf16.h>

#define NPTS 8192
#define NB   4
#define BLK  256
#define NREG 32                    // compact regions per (b,side)
#define CAP  NPTS
#define QPB  1024                  // dense queries per knn block (KMAX=4)
#define NQC  (NPTS / QPB)          // 8 chunks (worst case)
#define NSL  32                    // search slices over dense ids
#define SMAX 257                   // ceil(8192/32)=256 max staged +1 pad
#define THR  3.33f

// workspace layout:
//   ctl[0..511]      (words)  tickets qi*32, done2 @256, meanv @288..295
//   byte 4096        bcnt[8*NREG] u32
//   byte 8192        psum[64] f32   (written unconditionally by final)
//   byte 12288       pcnt[64] f32
//   byte 16384       part[8][NSL][NPTS] f32 = 8 MB (valid dense slots only)
//   byte 16384+8MB   pts[8*CAP] float4 (region-packed, encoded)
#define OFF_BCNT 4096
#define OFF_PSUM 8192
#define OFF_PCNT 12288
#define OFF_PART 16384
#define OFF_PTS  (16384 + 8 * NSL * NPTS * 4)

// ---- helpers ---------------------------------------------------------------

// wave-0 inclusive shfl-scan of one side's region counts -> P[0..NREG] in LDS
__device__ __forceinline__ void build_prefix(const unsigned* __restrict__ bcnt,
                                             int qi, int* P, int tid) {
    if (tid < 64) {
        const int lane = tid & 63;
        int v = (lane < NREG) ? (int)bcnt[qi * NREG + lane] : 0;
#pragma unroll
        for (int o = 1; o < NREG; o <<= 1) {
            int t = __shfl_up(v, o);
            if (lane >= o) v += t;
        }
        if (lane < NREG) P[lane + 1] = v;
        if (lane == 0) P[0] = 0;
    }
}

// largest r in [0,NREG) with P[r] <= id (branchless 5-step)
__device__ __forceinline__ int map_region(const int* P, int id) {
    int r = 0;
#pragma unroll
    for (int s = 16; s; s >>= 1)
        if (P[r + s] <= id) r += s;
    return r;
}

// ---------------------------------------------------------------------------
// compact: region-pack valid points, encoded (2x,2y,2z,-(x^2+y^2+z^2)).
// side 0 = warped src (Ps+F, Ms), side 1 = dst (Pd, Md). Block 0 zeroes ctl.
// ---------------------------------------------------------------------------
__global__ __launch_bounds__(BLK) void compact_kernel(
    const float* __restrict__ Ps, const float* __restrict__ Pd,
    const float* __restrict__ F,  const int* __restrict__ Ms,
    const int* __restrict__ Md,   unsigned* __restrict__ bcnt,
    float4* __restrict__ pts,     unsigned* __restrict__ ctl)
{
    const int b = blockIdx.z, side = blockIdx.y, r = blockIdx.x;
    const int qi = b * 2 + side;
    const int tid = threadIdx.x;
    const int g = b * NPTS + r * BLK + tid;

    if (r == 0 && side == 0 && b == 0)
        for (int i = tid; i < 512; i += BLK) ctl[i] = 0;

    float x, y, z; int v;
    if (side == 0) {
        x = Ps[3 * g + 0] + F[3 * g + 0];
        y = Ps[3 * g + 1] + F[3 * g + 1];
        z = Ps[3 * g + 2] + F[3 * g + 2];
        v = Ms[g];
    } else {
        x = Pd[3 * g + 0]; y = Pd[3 * g + 1]; z = Pd[3 * g + 2];
        v = Md[g];
    }
    const bool valid = v > 0;

    const int lane = tid & 63, w = tid >> 6;
    unsigned long long m = __ballot(valid);
    const int my = __popcll(m & ((1ull << lane) - 1ull));
    __shared__ int wc[4];
    if (lane == 0) wc[w] = __popcll(m);
    __syncthreads();
    int off = 0;
#pragma unroll
    for (int i = 0; i < 4; ++i) if (i < w) off += wc[i];
    if (valid)
        pts[(size_t)qi * CAP + r * BLK + off + my] =
            make_float4(2.f * x, 2.f * y, 2.f * z, -(x * x + y * y + z * z));
    if (tid == 0)
        bcnt[qi * NREG + r] = (unsigned)(wc[0] + wc[1] + wc[2] + wc[3]);
}

// ---------------------------------------------------------------------------
// knn: block = (chunk qc, slice sl, dir, b). Dense queries (KMAX=4 always)
// in registers, dense search slice staged in LDS with +1 pad. Inner loop
// uses cur/nxt prefetch so the ds_read for j+1 issues before j's 16 VALU.
// Per-slice maxima stored to part with plain coalesced stores.
// ---------------------------------------------------------------------------
__global__ __launch_bounds__(BLK) void knn_kernel(
    const unsigned* __restrict__ bcnt, const float4* __restrict__ pts,
    float* __restrict__ part)
{
    const int b = blockIdx.z, d = blockIdx.y;
    const int qc = blockIdx.x / NSL, sl = blockIdx.x % NSL;
    const int qi = b * 2 + d;
    const int si = b * 2 + (1 - d);
    const int tid = threadIdx.x;

    __shared__ int Pq[NREG + 1], Psx[NREG + 1];
    __shared__ float4 sp[SMAX];

    if (tid < 64) {                       // dual prefix scan in one wave
        const int lane = tid & 63;
        int vq = (lane < NREG) ? (int)bcnt[qi * NREG + lane] : 0;
        int vs = (lane < NREG) ? (int)bcnt[si * NREG + lane] : 0;
#pragma unroll
        for (int o = 1; o < NREG; o <<= 1) {
            int tq = __shfl_up(vq, o);
            int ts = __shfl_up(vs, o);
            if (lane >= o) { vq += tq; vs += ts; }
        }
        if (lane < NREG) { Pq[lane + 1] = vq; Psx[lane + 1] = vs; }
        if (lane == 0) { Pq[0] = 0; Psx[0] = 0; }
    }
    __syncthreads();

    const int nq = Pq[NREG], ns = Psx[NREG];
    if (qc * QPB >= nq) return;                    // block-uniform exit
    const int L = (ns + NSL - 1) / NSL;
    const int start = sl * L;
    int len = ns - start; if (len > L) len = L;
    if (len <= 0) return;                          // block-uniform exit

    if (tid < len) {                               // len <= 256 = BLK
        const int id = start + tid;
        const int r = map_region(Psx, id);
        sp[tid] = pts[(size_t)si * CAP + r * BLK + (id - Psx[r])];
    }
    if (tid == 0) sp[len] = make_float4(0.f, 0.f, 0.f, -1e30f);  // prefetch pad
    __syncthreads();

    float qx[4], qy[4], qz[4], bt[4];
    bool qv[4];
#pragma unroll
    for (int k = 0; k < 4; ++k) {
        const int q = qc * QPB + k * BLK + tid;
        qv[k] = q < nq;
        const int qq = qv[k] ? q : 0;
        const int r = map_region(Pq, qq);
        const float4 p = pts[(size_t)qi * CAP + r * BLK + (qq - Pq[r])];
        qx[k] = 0.5f * p.x; qy[k] = 0.5f * p.y; qz[k] = 0.5f * p.z;
        bt[k] = -1e30f;
    }

    float4 cur = sp[0];
#pragma unroll 2
    for (int j = 0; j < len; ++j) {
        const float4 nxt = sp[j + 1];              // prefetch next (pad-safe)
#pragma unroll
        for (int k = 0; k < 4; ++k) {
            float t = fmaf(qx[k], cur.x, cur.w);
            t = fmaf(qy[k], cur.y, t);
            t = fmaf(qz[k], cur.z, t);
            bt[k] = fmaxf(bt[k], t);
        }
        cur = nxt;
    }

    float* pb = part + ((size_t)qi * NSL + sl) * NPTS + qc * QPB;
#pragma unroll
    for (int k = 0; k < 4; ++k)
        if (qv[k]) pb[k * BLK + tid] = bt[k];      // coalesced plain store
}

// ---------------------------------------------------------------------------
// final: block = (qc, dir, b), 64 blocks. Max over NSL slice partials,
// d = |q|^2 - t, threshold, block-reduce, 2-level shallow ticket -> out[0].
// ---------------------------------------------------------------------------
__global__ __launch_bounds__(BLK) void final_kernel(
    const unsigned* __restrict__ bcnt, const float4* __restrict__ pts,
    const float* __restrict__ part, unsigned* __restrict__ ctl,
    float* __restrict__ out)
{
    const int b = blockIdx.z, dir = blockIdx.y, qc = blockIdx.x;
    const int qi = b * 2 + dir;
    const int tid = threadIdx.x, lane = tid & 63, w = tid >> 6;

    __shared__ int Pq[NREG + 1];
    build_prefix(bcnt, qi, Pq, tid);
    __syncthreads();
    const int nq = Pq[NREG];

    const float* pp = part + (size_t)qi * NSL * NPTS + qc * QPB;
    float s = 0.f, c = 0.f;
#pragma unroll
    for (int k = 0; k < 4; ++k) {
        const int q = qc * QPB + k * BLK + tid;
        if (q < nq) {
            const int r = map_region(Pq, q);
            const float4 p = pts[(size_t)qi * CAP + r * BLK + (q - Pq[r])];
            float m = -1e30f;
#pragma unroll
            for (int sl = 0; sl < NSL; ++sl)
                m = fmaxf(m, pp[(size_t)sl * NPTS + k * BLK + tid]);
            const float dd = fmaxf((-p.w) - m, 0.f);
            if (dd < THR) { s += dd; c += 1.f; }
        }
    }
#pragma unroll
    for (int off = 32; off; off >>= 1) {
        s += __shfl_down(s, off);
        c += __shfl_down(c, off);
    }
    __shared__ float red[8];
    if (lane == 0) { red[w] = s; red[4 + w] = c; }
    __syncthreads();
    if (tid == 0) {
        float* psum  = (float*)((char*)ctl + OFF_PSUM  - 0) + 0;  // see layout
        float* pcnt_ = (float*)((char*)ctl + OFF_PCNT);
        float* psum_ = (float*)((char*)ctl + OFF_PSUM);
        float* meanv = (float*)(ctl + 288);
        (void)psum;
        psum_[qi * NQC + qc] = red[0] + red[1] + red[2] + red[3];
        pcnt_[qi * NQC + qc] = red[4] + red[5] + red[6] + red[7];
        const unsigned r = __hip_atomic_fetch_add(&ctl[qi * 32], 1u,
                              __ATOMIC_ACQ_REL, __HIP_MEMORY_SCOPE_AGENT);
        if (r == NQC - 1) {                 // last block of this qi
            float S = 0.f, C = 0.f;
            for (int g = 0; g < NQC; ++g) {
                S += psum_[qi * NQC + g];
                C += pcnt_[qi * NQC + g];
            }
            meanv[qi] = S / C;
            const unsigned r2 = __hip_atomic_fetch_add(&ctl[256], 1u,
                                   __ATOMIC_ACQ_REL, __HIP_MEMORY_SCOPE_AGENT);
            if (r2 == 2 * NB - 1) {         // very last qi
                float a = 0.f;
#pragma unroll
                for (int i = 0; i < 2 * NB; ++i) a += meanv[i];
                out[0] = a;
            }
        }
    }
}

extern "C" void kernel_launch(void* const* d_in, const int* in_sizes, int n_in,
                              void* d_out, int out_size, void* d_ws, size_t ws_size,
                              hipStream_t stream)
{
    const float* Ps = (const float*)d_in[0];   // points_src  [B,N,3]
    const float* Pd = (const float*)d_in[1];   // points_dst  [B,N,3]
    const float* F  = (const float*)d_in[2];   // flows_pred  [B,N,3]
    // d_in[3] = flows_gt (unused by reference)
    const int* Ms = (const int*)d_in[4];       // masks_src [B,N]
    const int* Md = (const int*)d_in[5];       // masks_dst [B,N]
    float* out = (float*)d_out;

    unsigned* ctl = (unsigned*)d_ws;
    unsigned* bcnt = (unsigned*)((char*)d_ws + OFF_BCNT);
    float* part = (float*)((char*)d_ws + OFF_PART);
    float4* pts = (float4*)((char*)d_ws + OFF_PTS);

    compact_kernel<<<dim3(NREG, 2, NB), BLK, 0, stream>>>(
        Ps, Pd, F, Ms, Md, bcnt, pts, ctl);

    knn_kernel<<<dim3(NQC * NSL, 2, NB), BLK, 0, stream>>>(bcnt, pts, part);

    final_kernel<<<dim3(NQC, 2, NB), BLK, 0, stream>>>(
        bcnt, pts, part, ctl, out);
}